// Round 9
// baseline (93.137 us; speedup 1.0000x reference)
//
#include <hip/hip_runtime.h>

#define NA 2048
#define CDIM 8
#define CONVF 332.07156f
#define BROWS 8          // sorted rows per block
#define THREADS 512      // 8 waves
#define APT 4            // atoms staged per thread (512*4 = 2048)
#define GRID (NA / BROWS)

// Single fused kernel: every block redundantly computes the chain-sort
// permutation + per-atom factors for all 2048 atoms into its own LDS, then
// processes its 8 sorted rows against the opposite-chain contiguous region.
// No inter-block dependencies; d_out zeroed by a prior 12-byte memset.
__global__ __launch_bounds__(THREADS) void fused_kernel(
    const float* __restrict__ X,
    const float* __restrict__ embs,
    const float* __restrict__ qs,
    const float* __restrict__ Ps,
    const float* __restrict__ w0,
    const float* __restrict__ s0,
    const int* __restrict__ chain,
    const float* __restrict__ sf_elec,
    const float* __restrict__ born,
    const float* __restrict__ die,
    const float* __restrict__ depth,
    const float* __restrict__ radius,
    float* __restrict__ d_out)
{
    const int b = blockIdx.x, t = threadIdx.x;
    const int lane = t & 63, wv = t >> 6;     // 8 waves

    __shared__ float4 sa[NA];                 // x, y, z, q          (sorted)
    __shared__ float4 sb[NA];                 // sfA, erA, edA, w0j  (sorted)
    __shared__ float  ssc[NA];                // 2*s0                (sorted)
    __shared__ int    sinv[NA];               // sorted slot -> orig idx
    __shared__ int    wtot[8];
    __shared__ float  fsum[8];
    __shared__ float4 srowB[BROWS];           // sfB, erB, edB, 0   (this block's rows)
    __shared__ float4 sps[BROWS];             // 0, Psx, Psy, Psz
    __shared__ float  se[8], sv[8];

    // ---------- phase 1: chain flags + block-wide prefix scan ----------
    const int ib = APT * t;
    const int4 cf = ((const int4*)chain)[t];
    const int f0 = (cf.x == 0), f1 = (cf.y == 0), f2 = (cf.z == 0), f3 = (cf.w == 0);
    const int cnt = f0 + f1 + f2 + f3;
    int x = cnt;
#pragma unroll
    for (int off = 1; off < 64; off <<= 1) {
        int y = __shfl_up(x, off);
        if (lane >= off) x += y;
    }
    if (lane == 63) wtot[wv] = x;
    __syncthreads();
    int wbase = 0, n0 = 0;
#pragma unroll
    for (int k = 0; k < 8; ++k) {
        int v = wtot[k];
        if (k < wv) wbase += v;
        n0 += v;
    }
    int run = wbase + x - cnt;                // #chain0 atoms before atom ib

    // hoist small factor vectors
    float fa[CDIM], fr[CDIM], fd[CDIM], fe[CDIM], fb[CDIM];
#pragma unroll
    for (int k = 0; k < CDIM; ++k) {
        fa[k] = sf_elec[k];                   // j-side elec
        fr[k] = radius[k];                    // j-side radius
        fd[k] = depth[k];                     // j-side depth
        fe[k] = die[k];
        fb[k] = born[k];
    }
    const float f16 = sf_elec[2 * CDIM];

    // ---------- phase 2: per-atom factors + sorted scatter into LDS ----------
    float es = 0.0f;
#pragma unroll
    for (int h = 0; h < APT; ++h) {
        const int i = ib + h;
        const int fh = (h == 0 ? f0 : h == 1 ? f1 : h == 2 ? f2 : f3);
        const int sl = fh ? run : n0 + (i - run);
        run += fh;

        float e[CDIM];
#pragma unroll
        for (int k = 0; k < CDIM; ++k) e[k] = embs[i * CDIM + k];
        float sfA = 0.f, rfA = 0.f, dfA = 0.f, dieV = 0.f, Rv = 0.f;
#pragma unroll
        for (int k = 0; k < CDIM; ++k) {
            sfA  += e[k] * fa[k];
            rfA  += e[k] * fr[k];
            dfA  += e[k] * fd[k];
            dieV += e[k] * fe[k];
            Rv   += e[k] * fb[k];
        }
        dieV += 1e-6f;
        Rv += 1.0f;
        const float q = qs[i];
        es += -(1.0f - 1.0f / dieV) * q / (Rv + 1e-6f);

        const float w0v = w0[i];
        sa[sl]  = make_float4(X[i * 3 + 0], X[i * 3 + 1], X[i * 3 + 2], q);
        sb[sl]  = make_float4(sfA, __expf(-rfA), __expf(-dfA),
                              sqrtf(w0v * w0v + 1e-6f));
        ssc[sl] = 2.0f * s0[i];
        sinv[sl] = i;
    }
    // E_self partials (consumed by block 0 only)
#pragma unroll
    for (int off = 32; off > 0; off >>= 1) es += __shfl_down(es, off);
    if (lane == 0) fsum[wv] = es;
    __syncthreads();

    // ---------- phase 3: this block's row-side factors ----------
    const int rbase = b * BROWS;
    if (t < BROWS) {
        const int orig = sinv[rbase + t];
        float e[CDIM];
#pragma unroll
        for (int k = 0; k < CDIM; ++k) e[k] = embs[orig * CDIM + k];
        float sfB = 0.f, rfB = 0.f, dfB = 0.f;
#pragma unroll
        for (int k = 0; k < CDIM; ++k) {
            sfB += e[k] * sf_elec[CDIM + k];
            rfB += e[k] * radius[CDIM + k];
            dfB += e[k] * depth[CDIM + k];
        }
        srowB[t] = make_float4(sfB, __expf(-rfB), __expf(-dfB), 0.0f);
        sps[t]   = make_float4(0.0f, Ps[orig * 3 + 0], Ps[orig * 3 + 1],
                               Ps[orig * 3 + 2]);
    }
    if (b == 0 && t == 0) {
        float tt = 0.f;
#pragma unroll
        for (int k = 0; k < 8; ++k) tt += fsum[k];
        d_out[2] = CONVF * 0.01f * tt;        // E_solv (direct write)
    }
    __syncthreads();

    // ---------- phase 4: row registers ----------
    float xi[BROWS], yi[BROWS], zi[BROWS], qi[BROWS];
    float sfB[BROWS], erB[BROWS], edB[BROWS];
    bool anyPs = false;
#pragma unroll
    for (int rt = 0; rt < BROWS; ++rt) {
        const float4 p  = sa[rbase + rt];
        const float4 rb = srowB[rt];
        const float4 pp = sps[rt];
        xi[rt] = p.x; yi[rt] = p.y; zi[rt] = p.z; qi[rt] = p.w;
        sfB[rt] = rb.x; erB[rt] = rb.y; edB[rt] = rb.z;
        anyPs = anyPs || (pp.y != 0.f) || (pp.z != 0.f) || (pp.w != 0.f);
    }
    const bool uniform = (rbase >= n0) || (rbase + BROWS <= n0);

    float acc_e[BROWS], acc_v[BROWS];
#pragma unroll
    for (int rt = 0; rt < BROWS; ++rt) { acc_e[rt] = 0.f; acc_v[rt] = 0.f; }

    // ---------- phase 5: pair loop ----------
    if (uniform && !anyPs) {
        // fast path: contiguous opposite-chain region, no dipole terms
        const bool r0 = (rbase < n0);
        const int jbeg = r0 ? n0 : 0;
        const int jend = r0 ? NA : n0;
        for (int j = jbeg + t; j < jend; j += THREADS) {
            const float4 A = sa[j];
            const float4 B = sb[j];
            const float  S = ssc[j];
#pragma unroll
            for (int rt = 0; rt < BROWS; ++rt) {
                const float dx = A.x - xi[rt], dy = A.y - yi[rt], dz = A.z - zi[rt];
                const float d2 = dx * dx + dy * dy + dz * dz + 3e-6f;
                const float D = sqrtf(d2);
                const float invD = __builtin_amdgcn_rcpf(D + 1e-6f);

                const float sf = B.x + sfB[rt] + invD * f16;
                acc_e[rt] += qi[rt] * A.w * invD * sf;

                const float sig_r = __builtin_amdgcn_rcpf(fmaf(B.y, erB[rt], 1.0f));
                const float s = S * fmaf(0.8f, sig_r, 0.4f);
                const float Dm = D - s;
                const float t1 = __expf(-Dm * Dm);
                const float ta = t1 * __expf(fmaf(0.6f, Dm, -0.09f));
                const float t2 = t1 * t1;
                const float t3 = t2 * t1;
                const float t4 = t2 * t2;
                const float t8 = t4 * t4;
                const float t10 = t8 * t2;
                const float attr = ta + t3 + t10;
                const float sig_d = __builtin_amdgcn_rcpf(fmaf(B.z, edB[rt], 1.0f));
                const float w = B.w * (sig_d + 0.5f);
                const float repl = 5.0f * __expf(-0.3f * D * d2);
                acc_v[rt] += repl - w * attr * (1.0f / 3.0f);
            }
        }
    } else {
        // general path: full j with XOR mask; optional dipole terms
        for (int j = t; j < NA; j += THREADS) {
            const float4 A = sa[j];
            const float4 B = sb[j];
            const float  S = ssc[j];
            const bool j0 = (j < n0);
            float pjx = 0.f, pjy = 0.f, pjz = 0.f;
            if (anyPs) {
                const int oj = sinv[j];
                pjx = Ps[oj * 3 + 0]; pjy = Ps[oj * 3 + 1]; pjz = Ps[oj * 3 + 2];
            }
#pragma unroll
            for (int rt = 0; rt < BROWS; ++rt) {
                const float m = (((rbase + rt) < n0) != j0) ? 1.0f : 0.0f;
                const float dx = A.x - xi[rt], dy = A.y - yi[rt], dz = A.z - zi[rt];
                const float d2 = dx * dx + dy * dy + dz * dz + 3e-6f;
                const float D = sqrtf(d2);
                const float invD = __builtin_amdgcn_rcpf(D + 1e-6f);

                const float sf = B.x + sfB[rt] + invD * f16;
                float ee = qi[rt] * A.w * invD * sf;
                if (anyPs) {
                    const float4 Pi = sps[rt];
                    const float vpx = dx + 1e-6f, vpy = dy + 1e-6f, vpz = dz + 1e-6f;
                    float vn = sqrtf(vpx * vpx + vpy * vpy + vpz * vpz);
                    vn = fmaxf(vn, 1e-12f);
                    const float OqP = (vpx * Pi.y + vpy * Pi.z + vpz * Pi.w) *
                                      __builtin_amdgcn_rcpf(vn);
                    const float OPP = Pi.y * pjx + Pi.z * pjy + Pi.w * pjz;
                    const float invD2 = invD * invD;
                    const float invD4 = invD2 * invD2;
                    const float invD6 = invD4 * invD2;
                    ee += OqP * invD4 + OPP * invD6;
                }
                acc_e[rt] += m * ee;

                const float sig_r = __builtin_amdgcn_rcpf(fmaf(B.y, erB[rt], 1.0f));
                const float s = S * fmaf(0.8f, sig_r, 0.4f);
                const float Dm = D - s;
                const float t1 = __expf(-Dm * Dm);
                const float ta = t1 * __expf(fmaf(0.6f, Dm, -0.09f));
                const float t2 = t1 * t1;
                const float t3 = t2 * t1;
                const float t4 = t2 * t2;
                const float t8 = t4 * t4;
                const float t10 = t8 * t2;
                const float attr = ta + t3 + t10;
                const float sig_d = __builtin_amdgcn_rcpf(fmaf(B.z, edB[rt], 1.0f));
                const float w = B.w * (sig_d + 0.5f);
                const float repl = 5.0f * __expf(-0.3f * D * d2);
                acc_v[rt] += m * (repl - w * attr * (1.0f / 3.0f));
            }
        }
    }

    // ---------- phase 6: block reduce + atomic ----------
    float ae = 0.f, av = 0.f;
#pragma unroll
    for (int rt = 0; rt < BROWS; ++rt) { ae += acc_e[rt]; av += acc_v[rt]; }
#pragma unroll
    for (int off = 32; off > 0; off >>= 1) {
        ae += __shfl_down(ae, off);
        av += __shfl_down(av, off);
    }
    if (lane == 0) { se[wv] = ae; sv[wv] = av; }
    __syncthreads();
    if (t == 0) {
        float te = 0.f, tv = 0.f;
#pragma unroll
        for (int k = 0; k < 8; ++k) { te += se[k]; tv += sv[k]; }
        atomicAdd(d_out + 1, 0.5f * CONVF * te);   // E_elec
        atomicAdd(d_out + 0, tv);                  // E_vdw
    }
}

extern "C" void kernel_launch(void* const* d_in, const int* in_sizes, int n_in,
                              void* d_out, int out_size, void* d_ws, size_t ws_size,
                              hipStream_t stream) {
    const float* X       = (const float*)d_in[0];
    const float* embs    = (const float*)d_in[1];
    const float* qs      = (const float*)d_in[2];
    const float* Ps      = (const float*)d_in[3];
    const float* w0      = (const float*)d_in[4];
    const float* s0      = (const float*)d_in[5];
    const int*   chain   = (const int*)d_in[6];
    const float* sf_elec = (const float*)d_in[7];
    const float* born    = (const float*)d_in[8];
    const float* die     = (const float*)d_in[9];
    const float* depth   = (const float*)d_in[10];
    const float* radius  = (const float*)d_in[11];
    float* out = (float*)d_out;

    hipMemsetAsync(d_out, 0, 3 * sizeof(float), stream);
    fused_kernel<<<GRID, THREADS, 0, stream>>>(
        X, embs, qs, Ps, w0, s0, chain, sf_elec, born, die, depth, radius, out);
}